// Round 11
// baseline (411.158 us; speedup 1.0000x reference)
//
#include <hip/hip_runtime.h>

typedef unsigned short u16;
typedef __attribute__((ext_vector_type(8))) short bf16x8;
typedef __attribute__((ext_vector_type(4))) float f32x4;

__device__ inline float bf2f(u16 h) {
    union { unsigned u; float f; } v; v.u = ((unsigned)h) << 16; return v.f;
}
__device__ inline u16 f2bf(float f) {
    union { float f; unsigned u; } v; v.f = f;
    unsigned r = v.u + 0x7fffu + ((v.u >> 16) & 1u);
    return (u16)(r >> 16);
}

__device__ inline void gl_lds16(const u16* g, u16* l) {
    __builtin_amdgcn_global_load_lds(
        (const __attribute__((address_space(1))) void*)g,
        (__attribute__((address_space(3))) void*)l, 16, 0, 0);
}

__device__ __forceinline__ void wgbar() {
    asm volatile("" ::: "memory");
    __builtin_amdgcn_s_barrier();
    asm volatile("" ::: "memory");
}
#define VMW(n) asm volatile("s_waitcnt vmcnt(" #n ")" ::: "memory")

// ---------------------------------------------------------------------------
// f32 -> bf16 elementwise convert, up to 4 arrays per launch.
// ---------------------------------------------------------------------------
__global__ __launch_bounds__(256) void cvt_bf16_k(
    const float* __restrict__ s0, u16* __restrict__ d0, long long n0,
    const float* __restrict__ s1, u16* __restrict__ d1, long long n1,
    const float* __restrict__ s2, u16* __restrict__ d2, long long n2,
    const float* __restrict__ s3, u16* __restrict__ d3, long long n3)
{
    int y = blockIdx.y;
    const float* s = (y == 0) ? s0 : (y == 1) ? s1 : (y == 2) ? s2 : s3;
    u16* d         = (y == 0) ? d0 : (y == 1) ? d1 : (y == 2) ? d2 : d3;
    long long n    = (y == 0) ? n0 : (y == 1) ? n1 : (y == 2) ? n2 : n3;
    for (long long i = (long long)blockIdx.x * 256 + threadIdx.x; i < n;
         i += (long long)gridDim.x * 256) {
        float4 v = ((const float4*)s)[i];
        union { u16 h[4]; unsigned long long u; } p;
        p.h[0] = f2bf(v.x); p.h[1] = f2bf(v.y);
        p.h[2] = f2bf(v.z); p.h[3] = f2bf(v.w);
        ((unsigned long long*)d)[i] = p.u;
    }
}

// ---------------------------------------------------------------------------
// 8-phase 256x256 GEMM (faithful re-derivation of the documented template):
//   C[M,N] = (A[M,K] @ Bt[N,K]^T)*scale + bias.  ldb == K for all users.
// 512 thr = 8 waves (2M x 4N), wave tile 128x64, acc[8][4], BK=64.
// LDS 128KB: As/Bs[2 slots][2 halves][128][64] bf16, conflict-free BK=64
// swizzle (col-group ^= row&7, inverse-swizzled global source).
// Per iter (tiles t0 even/slot0, t1 odd/slot1), 8 phases of
//   {ds-reads ; 1 half-tile stage (2 gl_lds) ; [VMW] ; bar ; 16 MFMA ; bar}
// Reads: A 4/phase (quadrant mq x ks); B 4 in ph1,2,5,6 only (reg-held b0/b1,
// reused in ph3,4,7,8) so B LDS regions free after ph2/ph6.
// Stages ph1..8 = [t1.A0, t1.A1, t2.B0, t2.B1, t2.A0, t2.A1, t3.B0, t3.B1].
// VMW(4) at ph4 (confirms t1.{B0,B1,A0,A1} = all of ph5-8's needs) and ph8
// (confirms t2 fully). Entering each iter, outstanding = {t1.B0, t1.B1}.
// Never vmcnt(0) mid-loop; last iter: VMW(0) at ph4, no wait at ph8.
// Every stage >=1 barrier-pair after its region's last read (audited).
// ---------------------------------------------------------------------------
#define PSTA(T, H)                                                            \
    { const u16* g_ = Ag + (long long)((H) * 128 + w * 8 + srow) * K          \
                      + (long long)(T) * 64 + scol;                           \
      gl_lds16(g_, &As[(T) & 1][H][w * 512]);                                 \
      gl_lds16(g_ + 64LL * K, &As[(T) & 1][H][4096 + w * 512]); }

#define PSTB(T, H)                                                            \
    { const u16* g_ = Bg + (long long)(bn0 + (H) * 128 + w * 8 + srow) * K    \
                      + (long long)(T) * 64 + scol;                           \
      gl_lds16(g_, &Bs[(T) & 1][H][w * 512]);                                 \
      gl_lds16(g_ + 64LL * K, &Bs[(T) & 1][H][4096 + w * 512]); }

#define PREADA(SL, MQ, KS)                                                    \
    _Pragma("unroll")                                                         \
    for (int ii = 0; ii < 4; ii++)                                            \
        a_[ii] = *(const bf16x8*)&As[SL][wm2][                                \
            (((MQ) * 64 + ii * 16 + lane15) * 64 + (KS) * 32 + quad * 8) ^ xr];

#define PREADB(SL, KS, DST)                                                   \
    _Pragma("unroll")                                                         \
    for (int jj = 0; jj < 4; jj++)                                            \
        DST[jj] = *(const bf16x8*)&Bs[SL][wn2 >> 1][                          \
            (((wn2 & 1) * 64 + jj * 16 + lane15) * 64 + (KS) * 32 + quad * 8) ^ xr];

#define PMMA(MQ, BV)                                                          \
    __builtin_amdgcn_s_setprio(1);                                            \
    _Pragma("unroll")                                                         \
    for (int ii = 0; ii < 4; ii++)                                            \
        _Pragma("unroll")                                                     \
        for (int jj = 0; jj < 4; jj++)                                        \
            acc[(MQ) * 4 + ii][jj] = __builtin_amdgcn_mfma_f32_16x16x32_bf16( \
                a_[ii], BV[jj], acc[(MQ) * 4 + ii][jj], 0, 0, 0);             \
    __builtin_amdgcn_s_setprio(0);

template <int COUTF32, int NSPLIT>
__global__ __launch_bounds__(512, 1) void gemm8p(
    const u16* __restrict__ A, const u16* __restrict__ Bt,
    const float* __restrict__ bias0, const float* __restrict__ bias1,
    void* __restrict__ C0, void* __restrict__ C1,
    int M, int N, int K, float scale,
    long long sAb, long long sBb, long long sCb)
{
    __shared__ u16 As[2][2][8192];
    __shared__ u16 Bs[2][2][8192];

    // XCD-aware bijective swizzle (total blocks % 8 == 0), N-tile fastest.
    int gx = gridDim.x, gy = gridDim.y;
    int n = gx * gy * gridDim.z;
    int flat = (blockIdx.z * gy + blockIdx.y) * gx + blockIdx.x;
    int L = (flat & 7) * (n >> 3) + (flat >> 3);
    int bz = L / (gx * gy);
    int rr = L - bz * gx * gy;
    int bx = rr / gy, by = rr - bx * gy;

    int bm0 = bx * 256, bn0 = by * 256, b = bz;
    int tid = threadIdx.x;
    int w = tid >> 6, l = tid & 63;
    int wm2 = w >> 2;            // M half (128 rows)
    int wn2 = w & 3;             // N quarter (64 cols)
    int lane15 = l & 15, quad = l >> 4;
    int xr = (l & 7) << 3;       // read swizzle; read row&7 == l&7

    int srow = l >> 3;
    int scol = ((l & 7) ^ srow) * 8;   // inverse-swizzled source col-group

    const u16* Ag = A  + (long long)b * sAb + (long long)bm0 * K;
    const u16* Bg = Bt + (long long)b * sBb;

    f32x4 acc[8][4];
#pragma unroll
    for (int i = 0; i < 8; i++)
#pragma unroll
        for (int j = 0; j < 4; j++) acc[i][j] = (f32x4)(0.0f);

    int NT  = K >> 6;
    int NT2 = K >> 7;

    // Prologue: queue = [t0.B0, t0.B1, t0.A0, t0.A1, t1.B0, t1.B1] (12 loads)
    // VMW(4) confirms t0 fully, leaves {t1.B0, t1.B1}.
    PSTB(0, 0); PSTB(0, 1); PSTA(0, 0); PSTA(0, 1); PSTB(1, 0); PSTB(1, 1);
    VMW(4);
    wgbar();

    for (int j = 0; j < NT2; ++j) {
        int t1 = 2 * j + 1, t2 = 2 * j + 2, t3 = 2 * j + 3;
        bool pf = (t2 < NT);
        bf16x8 a_[4], b0_[4], b1_[4];

        // ph1: t0 (mq0,ks0); stage t1.A0
        PREADA(0, 0, 0); PREADB(0, 0, b0_);
        PSTA(t1, 0);
        wgbar(); PMMA(0, b0_); wgbar();
        // ph2: t0 (mq0,ks1); stage t1.A1
        PREADA(0, 0, 1); PREADB(0, 1, b1_);
        PSTA(t1, 1);
        wgbar(); PMMA(0, b1_); wgbar();
        // ph3: t0 (mq1,ks0), b0 reused; stage t2.B0 (B slot0 free after ph2)
        PREADA(0, 1, 0);
        if (pf) PSTB(t2, 0);
        wgbar(); PMMA(1, b0_); wgbar();
        // ph4: t0 (mq1,ks1), b1 reused; stage t2.B1; VMW(4) confirms t1 all
        PREADA(0, 1, 1);
        if (pf) { PSTB(t2, 1); VMW(4); } else { VMW(0); }
        wgbar(); PMMA(1, b1_); wgbar();
        // ph5: t1 (mq0,ks0); stage t2.A0 (A slot0 free after ph4)
        PREADA(1, 0, 0); PREADB(1, 0, b0_);
        if (pf) PSTA(t2, 0);
        wgbar(); PMMA(0, b0_); wgbar();
        // ph6: t1 (mq0,ks1); stage t2.A1
        PREADA(1, 0, 1); PREADB(1, 1, b1_);
        if (pf) PSTA(t2, 1);
        wgbar(); PMMA(0, b1_); wgbar();
        // ph7: t1 (mq1,ks0); stage t3.B0 (B slot1 free after ph6)
        PREADA(1, 1, 0);
        if (pf) PSTB(t3, 0);
        wgbar(); PMMA(1, b0_); wgbar();
        // ph8: t1 (mq1,ks1); stage t3.B1; VMW(4) confirms t2 all
        PREADA(1, 1, 1);
        if (pf) { PSTB(t3, 1); VMW(4); }
        wgbar(); PMMA(1, b1_); wgbar();
    }

    // Epilogue (R6-verified layout): col = lane15 (frag jj),
    // row = (i>>2)*64 + (i&3)*16 + quad*4 + r  == i*16 + quad*4 + r.
#pragma unroll
    for (int jj = 0; jj < 4; jj++) {
        int col = bn0 + wn2 * 64 + jj * 16 + lane15;
        int seg, cl, cstride;
        if (NSPLIT == 1) { seg = 0; cl = col; cstride = N; }
        else             { seg = col >> 10; cl = col & 1023; cstride = 1024; }
        const float* bp = (seg == 0) ? bias0 : bias1;
        void* cb = (seg == 0) ? C0 : C1;
        u16*   c16 = (u16*)cb   + (long long)b * sCb;
        float* c32 = (float*)cb + (long long)b * sCb;
        float bvc = bp ? bp[cl] : 0.0f;
#pragma unroll
        for (int i = 0; i < 8; i++) {
            int row0 = bm0 + wm2 * 128 + i * 16 + quad * 4;
#pragma unroll
            for (int r = 0; r < 4; r++) {
                float v = acc[i][jj][r] * scale + bvc;
                if (COUTF32) c32[(long long)(row0 + r) * cstride + cl] = v;
                else         c16[(long long)(row0 + r) * cstride + cl] = f2bf(v);
            }
        }
    }
}

// ---------------------------------------------------------------------------
// Occupancy-3 ring GEMM body (R9/R10, kept for PV and Vt).
// ---------------------------------------------------------------------------
#define OSTA(T, SL2, S)                                                       \
    { const u16* g_ = Ag + (long long)((S) * 64 + w * 16 + orow) * K          \
                      + (long long)(T) * 32 + oscol;                          \
      gl_lds16(g_, &As[(SL2) * 4096 + (S) * 2048 + w * 512]); }

#define OSTB(T, SL2, S)                                                       \
    { const u16* g_ = Bg + (long long)(bn0 + (S) * 64 + w * 16 + orow) * ldb  \
                      + (long long)(T) * 32 + oscol;                          \
      gl_lds16(g_, &Bs[(SL2) * 4096 + (S) * 2048 + w * 512]); }

template <int COUTF32, int BIASROW, int NSPLIT, int GATE>
__device__ __forceinline__ void gemm_body(
    const u16* __restrict__ A, const u16* __restrict__ Bt,
    const float* __restrict__ bias0, const float* __restrict__ bias1,
    void* __restrict__ C0, void* __restrict__ C1,
    int M, int N, int K, int ldb, float scale,
    long long sAb, long long sBb, long long sCb, long long bofs_stride,
    int bx, int by, int bz, int tid,
    const float* __restrict__ Wg, float* __restrict__ gatebuf,
    u16* lds)
{
    u16* As = lds;              // 3 x 4096
    u16* Bs = lds + 12288;      // 3 x 4096

    int bm0 = bx * 128;
    int bn0 = by * 128;
    int b   = bz;
    int w = tid >> 6, l = tid & 63;
    int wm = w >> 1;
    int wn = w & 1;
    int lane15 = l & 15, quad = l >> 4;
    int xr = (l & 3) << 3;

    int orow  = l >> 2;
    int oscol = ((l & 3) ^ (orow & 3)) * 8;

    const u16* Ag = A  + (long long)b * sAb + (long long)bm0 * K;
    const u16* Bg = Bt + (long long)b * sBb + (long long)(bm0 >> 11) * bofs_stride;

    f32x4 acc[4][4];
#pragma unroll
    for (int i = 0; i < 4; i++)
#pragma unroll
        for (int j = 0; j < 4; j++) acc[i][j] = (f32x4)(0.0f);

    int NT = K >> 5;

    OSTA(0, 0, 0); OSTA(0, 0, 1); OSTB(0, 0, 0); OSTB(0, 0, 1);
    OSTA(1, 1, 0); OSTA(1, 1, 1); OSTB(1, 1, 0); OSTB(1, 1, 1);
    VMW(4);
    wgbar();

    int sl = 0, sl2 = 2;
    for (int t = 0; t < NT; ++t) {
        bf16x8 av[4], bvv[4];
#pragma unroll
        for (int ii = 0; ii < 4; ii++)
            av[ii] = *(const bf16x8*)&As[sl * 4096 +
                (wm * 64 + ii * 16 + lane15) * 32 + ((quad * 8) ^ xr)];
#pragma unroll
        for (int jj = 0; jj < 4; jj++)
            bvv[jj] = *(const bf16x8*)&Bs[sl * 4096 +
                (wn * 64 + jj * 16 + lane15) * 32 + ((quad * 8) ^ xr)];

        if (t + 2 < NT) {
            int t2 = t + 2;
            OSTA(t2, sl2, 0); OSTA(t2, sl2, 1);
            OSTB(t2, sl2, 0); OSTB(t2, sl2, 1);
            VMW(4);
        } else if (t + 1 < NT) {
            VMW(0);
        }
        wgbar();

        __builtin_amdgcn_s_setprio(1);
#pragma unroll
        for (int ii = 0; ii < 4; ii++)
#pragma unroll
            for (int jj = 0; jj < 4; jj++)
                acc[ii][jj] = __builtin_amdgcn_mfma_f32_16x16x32_bf16(
                    av[ii], bvv[jj], acc[ii][jj], 0, 0, 0);
        __builtin_amdgcn_s_setprio(0);
        wgbar();

        sl  = (sl  == 2) ? 0 : sl + 1;
        sl2 = (sl2 == 2) ? 0 : sl2 + 1;
    }

    float rowb_[4][4];
    if (BIASROW) {
#pragma unroll
        for (int i = 0; i < 4; i++)
#pragma unroll
            for (int r = 0; r < 4; r++)
                rowb_[i][r] = bias0[bm0 + wm * 64 + i * 16 + quad * 4 + r];
    }
    float gsum = 0.0f;
#pragma unroll
    for (int jj = 0; jj < 4; jj++) {
        int col = bn0 + wn * 64 + jj * 16 + lane15;
        int seg, cl, cstride;
        if (NSPLIT == 1) { seg = 0; cl = col; cstride = N; }
        else             { seg = col >> 10; cl = col & 1023; cstride = 1024; }
        const float* bp = (seg == 0) ? bias0 : bias1;
        void* cb = (seg == 0) ? C0 : C1;
        u16*   c16 = (u16*)cb   + (long long)b * sCb;
        float* c32 = (float*)cb + (long long)b * sCb;
        float bvc = (!BIASROW && bp) ? bp[cl] : 0.0f;
        float wgc = GATE ? Wg[cl] : 0.0f;
#pragma unroll
        for (int i = 0; i < 4; i++) {
            int row0 = bm0 + wm * 64 + i * 16 + quad * 4;
#pragma unroll
            for (int r = 0; r < 4; r++) {
                float v = acc[i][jj][r] * scale + (BIASROW ? rowb_[i][r] : bvc);
                if (GATE) gsum += v * wgc;
                if (COUTF32) c32[(long long)(row0 + r) * cstride + cl] = v;
                else         c16[(long long)(row0 + r) * cstride + cl] = f2bf(v);
            }
        }
    }
    if (GATE) {
#pragma unroll
        for (int o = 32; o > 0; o >>= 1) gsum += __shfl_xor(gsum, o);
        float* red = (float*)lds;
        __syncthreads();
        if ((tid & 63) == 0) red[tid >> 6] = gsum;
        __syncthreads();
        if (tid == 0)
            atomicAdd(&gatebuf[bm0 >> 11],
                      red[0] + red[1] + red[2] + red[3]);
    }
}

template <int COUTF32, int BIASROW, int NSPLIT, int NFAST, int GATE>
__global__ __launch_bounds__(256, 3) void gemm_o(
    const u16* __restrict__ A, const u16* __restrict__ Bt,
    const float* __restrict__ bias0, const float* __restrict__ bias1,
    void* __restrict__ C0, void* __restrict__ C1,
    int M, int N, int K, int ldb, float scale,
    long long sAb, long long sBb, long long sCb, long long bofs_stride,
    const float* __restrict__ Wg, float* __restrict__ gatebuf)
{
    __shared__ u16 lds[24576];

    int gx = gridDim.x, gy = gridDim.y;
    int n = gx * gy * gridDim.z;
    int flat = (blockIdx.z * gy + blockIdx.y) * gx + blockIdx.x;
    int L = (flat & 7) * (n >> 3) + (flat >> 3);
    int bz = L / (gx * gy);
    int rr = L - bz * gx * gy;
    int bx, by;
    if (NFAST) { bx = rr / gy; by = rr - bx * gy; }
    else       { by = rr / gx; bx = rr - by * gx; }

    gemm_body<COUTF32, BIASROW, NSPLIT, GATE>(
        A, Bt, bias0, bias1, C0, C1, M, N, K, ldb, scale,
        sAb, sBb, sCb, bofs_stride, bx, by, bz, threadIdx.x, Wg, gatebuf, lds);
}

// ---------------------------------------------------------------------------
// Row softmax in-place; block 0 zeroes the 4-float gate accumulator.
// ---------------------------------------------------------------------------
__global__ __launch_bounds__(256) void softmax_k(u16* __restrict__ Sc,
                                                 float* __restrict__ gatebuf)
{
    long long row = blockIdx.x;
    u16* s = Sc + row * 2048;
    int t = threadIdx.x;
    if (blockIdx.x == 0 && t < 4) gatebuf[t] = 0.0f;

    uint4 raw = *(const uint4*)(s + t * 8);
    const u16* rp = (const u16*)&raw;
    float v[8];
    float mx = -3.4e38f;
#pragma unroll
    for (int j = 0; j < 8; j++) { v[j] = bf2f(rp[j]); mx = fmaxf(mx, v[j]); }
#pragma unroll
    for (int o = 32; o > 0; o >>= 1) mx = fmaxf(mx, __shfl_xor(mx, o));
    __shared__ float redm[4];
    if ((t & 63) == 0) redm[t >> 6] = mx;
    __syncthreads();
    mx = fmaxf(fmaxf(redm[0], redm[1]), fmaxf(redm[2], redm[3]));

    float sum = 0.0f;
#pragma unroll
    for (int j = 0; j < 8; j++) { v[j] = __expf(v[j] - mx); sum += v[j]; }
#pragma unroll
    for (int o = 32; o > 0; o >>= 1) sum += __shfl_xor(sum, o);
    __shared__ float reds[4];
    if ((t & 63) == 0) reds[t >> 6] = sum;
    __syncthreads();
    sum = reds[0] + reds[1] + reds[2] + reds[3];

    float inv = 1.0f / sum;
    u16 o8[8];
#pragma unroll
    for (int j = 0; j < 8; j++) o8[j] = f2bf(v[j] * inv);
    *(uint4*)(s + t * 8) = *(const uint4*)o8;
}

// ---------------------------------------------------------------------------
// Epilogue: LN(x + relu(mu + eps*exp(0.5*lv))); block 0 finishes the gate.
// ---------------------------------------------------------------------------
__global__ __launch_bounds__(256) void epilogue_k(
    const float* __restrict__ x, const float* __restrict__ ep,
    const float* __restrict__ mu, const float* __restrict__ lv,
    const float* __restrict__ gamma, const float* __restrict__ beta,
    float* __restrict__ out, const float* __restrict__ bg,
    float* __restrict__ pg)
{
    long long base = (long long)blockIdx.x * 1024;
    int t = threadIdx.x;
    int i0 = t * 4;
    if (blockIdx.x == 0 && t < 4) {
        float v = pg[t] * (1.0f / 2048.0f) + bg[0];
        pg[t] = 1.0f / (1.0f + __expf(-v));
    }

    float4 xv = *(const float4*)&x[base + i0];
    float4 ev = *(const float4*)&ep[base + i0];
    float4 mv = *(const float4*)&mu[base + i0];
    float4 lw = *(const float4*)&lv[base + i0];

    float y[4];
    y[0] = xv.x + fmaxf(mv.x + ev.x * __expf(0.5f * lw.x), 0.0f);
    y[1] = xv.y + fmaxf(mv.y + ev.y * __expf(0.5f * lw.y), 0.0f);
    y[2] = xv.z + fmaxf(mv.z + ev.z * __expf(0.5f * lw.z), 0.0f);
    y[3] = xv.w + fmaxf(mv.w + ev.w * __expf(0.5f * lw.w), 0.0f);

    float sum = 0.0f, sq = 0.0f;
#pragma unroll
    for (int j = 0; j < 4; j++) { sum += y[j]; sq += y[j] * y[j]; }
#pragma unroll
    for (int o = 32; o > 0; o >>= 1) { sum += __shfl_xor(sum, o); sq += __shfl_xor(sq, o); }
    __shared__ float rs[4], rq[4];
    if ((t & 63) == 0) { rs[t >> 6] = sum; rq[t >> 6] = sq; }
    __syncthreads();
    sum = rs[0] + rs[1] + rs[2] + rs[3];
    sq  = rq[0] + rq[1] + rq[2] + rq[3];
    float mean = sum * (1.0f / 1024.0f);
    float var  = fmaxf(sq * (1.0f / 1024.0f) - mean * mean, 0.0f);
    float rstd = rsqrtf(var + 1e-5f);

    float4 gv = *(const float4*)&gamma[i0];
    float4 bv = *(const float4*)&beta[i0];
    float4 o;
    o.x = (y[0] - mean) * rstd * gv.x + bv.x;
    o.y = (y[1] - mean) * rstd * gv.y + bv.y;
    o.z = (y[2] - mean) * rstd * gv.z + bv.z;
    o.w = (y[3] - mean) * rstd * gv.w + bv.w;
    *(float4*)&out[base + i0] = o;
}

// ---------------------------------------------------------------------------
extern "C" void kernel_launch(void* const* d_in, const int* in_sizes, int n_in,
                              void* d_out, int out_size, void* d_ws, size_t ws_size,
                              hipStream_t stream)
{
    const float* x     = (const float*)d_in[0];
    const float* ep    = (const float*)d_in[1];
    const float* Wq    = (const float*)d_in[2];
    const float* bq    = (const float*)d_in[3];
    const float* Wk    = (const float*)d_in[4];
    const float* bk    = (const float*)d_in[5];
    const float* Wv    = (const float*)d_in[6];
    const float* bv    = (const float*)d_in[7];
    const float* Wmu   = (const float*)d_in[8];
    const float* bmu   = (const float*)d_in[9];
    const float* Wlv   = (const float*)d_in[10];
    const float* blv   = (const float*)d_in[11];
    const float* Wg    = (const float*)d_in[12];
    const float* bg    = (const float*)d_in[13];
    const float* gamma = (const float*)d_in[14];
    const float* beta  = (const float*)d_in[15];
    float* out = (float*)d_out;

    const int M = 8192;       // B*S
    const int D = 1024;
    const int S = 2048;

    float* mu_out = out + 8388608LL;
    float* lv_out = out + 16777216LL;
    float* pg_out = out + 25165824LL;

    // Overlays (d_out dead regions; ws = h only):
    //  out region: xb | Wqb|Wkb | Wvb -> Sc -> Wmub|Wlvb (@+4MB) -> out f32
    //  mu region: Q | Kb -> mu_out; lv region: VtAll -> lv_out
    //  pg region: gate accumulator -> p_gate
    u16* xb   = (u16*)out;
    u16* Wqb  = (u16*)out + 8388608LL;     // [2048][1024]: Wq then Wk
    u16* Wkb  = (u16*)out + 9437184LL;
    u16* Wvb  = (u16*)out + 10485760LL;
    u16* Sc   = (u16*)out;
    u16* Q    = (u16*)mu_out;
    u16* Kb   = (u16*)mu_out + 8388608LL;
    u16* Vt   = (u16*)lv_out;              // VtAll [1024][8192]
    u16* h    = (u16*)d_ws;
    u16* Wmub = (u16*)out + 2097152LL;     // [2048][1024]: Wmu then Wlv
    u16* Wlvb = (u16*)out + 3145728LL;

    dim3 blk(256), blk8(512);

    // 0. Convert x, Wq, Wk, Wv to bf16.
    cvt_bf16_k<<<dim3(2048, 4), blk, 0, stream>>>(
        x,  xb,  2097152LL,
        Wq, Wqb, 262144LL,
        Wk, Wkb, 262144LL,
        Wv, Wvb, 262144LL);

    // 1. Q|K fused (8-phase 256^2): C[8192,2048] = xb @ [Wq;Wk]^T
    gemm8p<0, 2><<<dim3(32, 8, 1), blk8, 0, stream>>>(
        xb, Wqb, bq, bk, Q, Kb, M, 2048, D, 1.0f, 0, 0, 0);

    // 2. VtAll[1024,8192] = Wv @ x^T + bv(row)
    gemm_o<0, 1, 1, 0, 0><<<dim3(8, 64, 1), blk, 0, stream>>>(
        Wvb, xb, bv, nullptr, Vt, nullptr,
        D, 8192, D, D, 1.0f, 0, 0, 0, 0, nullptr, nullptr);

    // 3. scores = Q @ K^T / 48 per batch (8-phase 256^2)
    gemm8p<0, 1><<<dim3(8, 8, 4), blk8, 0, stream>>>(
        Q, Kb, nullptr, nullptr, Sc, nullptr,
        S, S, D, 1.0f / 48.0f,
        (long long)S * D, (long long)S * D, (long long)S * S);

    // 4. softmax in place (+ zero gate accumulator)
    softmax_k<<<dim3(8192), blk, 0, stream>>>(Sc, pg_out);

    // 5. h = P @ V (+ fused gate partials)
    gemm_o<0, 0, 1, 1, 1><<<dim3(64, 8, 1), blk, 0, stream>>>(
        Sc, Vt, nullptr, nullptr, h, nullptr,
        M, D, S, 8192, 1.0f, 0, 0, 0, 2048, Wg, pg_out);

    // 6. Convert Wmu, Wlv into dead Sc region.
    cvt_bf16_k<<<dim3(512, 2), blk, 0, stream>>>(
        Wmu, Wmub, 262144LL,
        Wlv, Wlvb, 262144LL,
        nullptr, nullptr, 0LL,
        nullptr, nullptr, 0LL);

    // 7. mu|lv fused (8-phase 256^2): C[8192,2048] = h @ [Wmu;Wlv]^T
    gemm8p<1, 2><<<dim3(32, 8, 1), blk8, 0, stream>>>(
        h, Wmub, bmu, blv, (void*)mu_out, (void*)lv_out,
        M, 2048, D, 1.0f, 0, 0, 0);

    // 8. out = LN(x + relu(mu + eps*exp(0.5*logvar))) (+ gate sigmoid)
    epilogue_k<<<dim3(8192), blk, 0, stream>>>(
        x, ep, mu_out, lv_out, gamma, beta, out, bg, pg_out);
}